// Round 2
// baseline (3006.644 us; speedup 1.0000x reference)
//
#include <hip/hip_runtime.h>
#include <hip/hip_bf16.h>

#define NN 100000
#define NE 640000
#define NG 512
#define NIN 64
#define EIN 16
#define H 128
#define H2 256
#define NL 4

// ---------------- node projection: h = relu(x @ node_w + node_b) ----------------
__global__ __launch_bounds__(256) void k_node_proj(const float* __restrict__ x,
                                                   const float* __restrict__ W,
                                                   const float* __restrict__ b,
                                                   float* __restrict__ h) {
    __shared__ float sW[NIN * H];  // 32 KB
    int tid = threadIdx.x;
    for (int i = tid; i < NIN * H; i += 256) sW[i] = W[i];
    __syncthreads();
    int c = tid & 127, half = tid >> 7;
    for (int node = blockIdx.x * 2 + half; node < NN; node += gridDim.x * 2) {
        const float* xr = x + (size_t)node * NIN;
        float acc = b[c];
#pragma unroll
        for (int k = 0; k < NIN; ++k) acc = fmaf(xr[k], sW[k * H + c], acc);
        h[(size_t)node * H + c] = fmaxf(acc, 0.f);
    }
}

// ------------- message + aggregate: agg[dst] += relu(h[src] + relu(ea@We+be)) -------------
__global__ __launch_bounds__(256) void k_msg_agg(const float* __restrict__ ea,
                                                 const int* __restrict__ src,
                                                 const int* __restrict__ dst,
                                                 const float* __restrict__ We,
                                                 const float* __restrict__ be,
                                                 const float* __restrict__ h,
                                                 float* __restrict__ agg) {
    __shared__ float sW[EIN * H];  // 8 KB
    __shared__ float sb[H];
    int tid = threadIdx.x;
    for (int i = tid; i < EIN * H; i += 256) sW[i] = We[i];
    if (tid < H) sb[tid] = be[tid];
    __syncthreads();
    int c = tid & 127, half = tid >> 7;
    for (int e = blockIdx.x * 2 + half; e < NE; e += gridDim.x * 2) {
        const float* ear = ea + (size_t)e * EIN;
        float acc = sb[c];
#pragma unroll
        for (int k = 0; k < EIN; ++k) acc = fmaf(ear[k], sW[k * H + c], acc);
        // reference applies relu to e once up front; relu(h_src + e) uses that e
        acc = fmaxf(acc, 0.f);
        int s = src[e], d = dst[e];
        float m = h[(size_t)s * H + c] + acc;
        m = fmaxf(m, 0.f);
        atomicAdd(&agg[(size_t)d * H + c], m);
    }
}

// ---- MLP per 32-node tile: z = h+agg; t = relu(z@w1+b1); z2 = t@w2+b2 -> agg; stats ----
__global__ __launch_bounds__(256) void k_mlp(const float* __restrict__ h,
                                             float* __restrict__ agg,  // in: agg, out: z2
                                             const float* __restrict__ w1,
                                             const float* __restrict__ b1,
                                             const float* __restrict__ w2,
                                             const float* __restrict__ b2,
                                             float* __restrict__ stats) {  // [2*H]: sum, sumsq
    __shared__ float sz[32 * H];   // 16 KB
    __shared__ float st[32 * H2];  // 32 KB
    int tid = threadIdx.x;
    int base = blockIdx.x * 32;  // 3125 * 32 == 100000 exactly
    // phase 1: z tile into LDS
    for (int i = tid; i < 32 * H; i += 256) {
        int n = base + (i >> 7);
        size_t idx = (size_t)n * H + (i & 127);
        sz[i] = h[idx] + agg[idx];
    }
    __syncthreads();
    // phase 2: t = relu(z @ w1 + b1); thread `tid` owns output column tid (0..255)
    {
        float acc[32];
        float bj = b1[tid];
#pragma unroll
        for (int n = 0; n < 32; ++n) acc[n] = bj;
        for (int k = 0; k < H; ++k) {
            float w = w1[(size_t)k * H2 + tid];
#pragma unroll
            for (int n = 0; n < 32; ++n) acc[n] = fmaf(sz[n * H + k], w, acc[n]);
        }
#pragma unroll
        for (int n = 0; n < 32; ++n) st[n * H2 + tid] = fmaxf(acc[n], 0.f);
    }
    __syncthreads();
    // phase 3: z2 = t @ w2 + b2; thread owns (col c, 16-node half)
    int c = tid & 127;
    int n0 = (tid >> 7) * 16;
    float acc2[16];
    float bc = b2[c];
#pragma unroll
    for (int n = 0; n < 16; ++n) acc2[n] = bc;
    for (int j = 0; j < H2; ++j) {
        float w = w2[(size_t)j * H + c];
#pragma unroll
        for (int n = 0; n < 16; ++n) acc2[n] = fmaf(st[(n0 + n) * H2 + j], w, acc2[n]);
    }
    float lsum = 0.f, lsq = 0.f;
#pragma unroll
    for (int n = 0; n < 16; ++n) {
        int node = base + n0 + n;
        agg[(size_t)node * H + c] = acc2[n];
        lsum += acc2[n];
        lsq += acc2[n] * acc2[n];
    }
    __syncthreads();  // all reads of st/sz done
    sz[tid] = lsum;
    sz[256 + tid] = lsq;
    __syncthreads();
    if (tid < H) {
        float s = sz[tid] + sz[tid + 128];
        float q = sz[256 + tid] + sz[256 + tid + 128];
        atomicAdd(&stats[tid], s);
        atomicAdd(&stats[H + tid], q);
    }
}

// ---------------- BN finalize: scale/shift from stats ----------------
__global__ void k_bn_fin(const float* __restrict__ stats, const float* __restrict__ gamma,
                         const float* __restrict__ beta, float* __restrict__ prm) {
    int c = threadIdx.x;  // 128
    float mean = stats[c] * (1.f / NN);
    float var = stats[H + c] * (1.f / NN) - mean * mean;
    float sc = gamma[c] * rsqrtf(var + 1e-5f);
    prm[c] = sc;
    prm[H + c] = beta[c] - mean * sc;
}

// ---------------- BN apply + relu: h = relu(z2*scale + shift) ----------------
__global__ __launch_bounds__(256) void k_bn_apply(const float* __restrict__ z2,
                                                  const float* __restrict__ prm,
                                                  float* __restrict__ h) {
    __shared__ float sp[2 * H];
    int tid = threadIdx.x;
    if (tid < 2 * H) sp[tid] = prm[tid];
    __syncthreads();
    const int total4 = NN * H / 4;
    for (int i = blockIdx.x * blockDim.x + tid; i < total4; i += gridDim.x * blockDim.x) {
        float4 v = ((const float4*)z2)[i];
        int c0 = (i * 4) & 127;
        v.x = fmaxf(v.x * sp[c0 + 0] + sp[H + c0 + 0], 0.f);
        v.y = fmaxf(v.y * sp[c0 + 1] + sp[H + c0 + 1], 0.f);
        v.z = fmaxf(v.z * sp[c0 + 2] + sp[H + c0 + 2], 0.f);
        v.w = fmaxf(v.w * sp[c0 + 3] + sp[H + c0 + 3], 0.f);
        ((float4*)h)[i] = v;
    }
}

// ---------------- global mean pool ----------------
__global__ __launch_bounds__(256) void k_pool(const float* __restrict__ h,
                                              const int* __restrict__ batch,
                                              float* __restrict__ sums,
                                              int* __restrict__ cnt) {
    const int total = NN * H;
    for (int i = blockIdx.x * blockDim.x + threadIdx.x; i < total;
         i += gridDim.x * blockDim.x) {
        int n = i >> 7, c = i & 127;
        int g = batch[n];
        atomicAdd(&sums[(size_t)g * H + c], h[i]);
        if (c == 0) atomicAdd(&cnt[g], 1);
    }
}

__global__ void k_pool_fin(const float* __restrict__ sums, const int* __restrict__ cnt,
                           float* __restrict__ out) {
    int i = blockIdx.x * blockDim.x + threadIdx.x;  // 65536 = NG*H
    if (i < NG * H) {
        int g = i >> 7;
        float cc = (float)cnt[g];
        out[i] = sums[i] / fmaxf(cc, 1.f);
    }
}

extern "C" void kernel_launch(void* const* d_in, const int* in_sizes, int n_in,
                              void* d_out, int out_size, void* d_ws, size_t ws_size,
                              hipStream_t stream) {
    const float* x      = (const float*)d_in[0];
    const int*   ei     = (const int*)d_in[1];
    const float* ea     = (const float*)d_in[2];
    const int*   batch  = (const int*)d_in[3];
    const float* node_w = (const float*)d_in[4];
    const float* node_b = (const float*)d_in[5];
    const float* edge_w = (const float*)d_in[6];
    const float* edge_b = (const float*)d_in[7];
    const float* w1     = (const float*)d_in[8];
    const float* b1     = (const float*)d_in[9];
    const float* w2     = (const float*)d_in[10];
    const float* b2     = (const float*)d_in[11];
    const float* gamma  = (const float*)d_in[12];
    const float* beta   = (const float*)d_in[13];
    float* out = (float*)d_out;

    char* ws = (char*)d_ws;
    const size_t SZ_H = (size_t)NN * H * 4;  // 51,200,000 B
    float* h     = (float*)(ws);
    float* agg   = (float*)(ws + SZ_H);
    float* stats = (float*)(ws + 2 * SZ_H);
    float* prm   = (float*)(ws + 2 * SZ_H + 1024);
    float* pool  = (float*)(ws + 2 * SZ_H + 2048);
    int*   cnt   = (int*)(ws + 2 * SZ_H + 2048 + (size_t)NG * H * 4);

    const int* srcp = ei;
    const int* dstp = ei + NE;

    k_node_proj<<<2048, 256, 0, stream>>>(x, node_w, node_b, h);

    for (int l = 0; l < NL; ++l) {
        hipMemsetAsync(agg, 0, SZ_H, stream);
        hipMemsetAsync(stats, 0, 2 * H * 4, stream);
        k_msg_agg<<<2048, 256, 0, stream>>>(ea, srcp, dstp, edge_w, edge_b, h, agg);
        k_mlp<<<3125, 256, 0, stream>>>(h, agg, w1 + (size_t)l * H * H2, b1 + (size_t)l * H2,
                                        w2 + (size_t)l * H2 * H, b2 + (size_t)l * H, stats);
        k_bn_fin<<<1, 128, 0, stream>>>(stats, gamma + (size_t)l * H, beta + (size_t)l * H, prm);
        k_bn_apply<<<1024, 256, 0, stream>>>(agg, prm, h);
    }

    hipMemsetAsync(pool, 0, (size_t)NG * H * 4 + NG * 4, stream);
    k_pool<<<2048, 256, 0, stream>>>(h, batch, pool, cnt);
    k_pool_fin<<<256, 256, 0, stream>>>(pool, cnt, out);
}

// Round 3
// 2081.168 us; speedup vs baseline: 1.4447x; 1.4447x over previous
//
#include <hip/hip_runtime.h>
#include <hip/hip_bf16.h>

#define NN 100000
#define NE 640000
#define NG 512
#define NIN 64
#define EIN 16
#define H 128
#define H2 256
#define NL 4

// ---------------- node projection: X = relu(x @ node_w + node_b) ----------------
__global__ __launch_bounds__(256) void k_node_proj(const float* __restrict__ x,
                                                   const float* __restrict__ W,
                                                   const float* __restrict__ b,
                                                   float* __restrict__ h) {
    __shared__ float sW[NIN * H];  // 32 KB
    int tid = threadIdx.x;
    for (int i = tid; i < NIN * H; i += 256) sW[i] = W[i];
    __syncthreads();
    int c = tid & 127, half = tid >> 7;
    for (int node = blockIdx.x * 2 + half; node < NN; node += gridDim.x * 2) {
        const float* xr = x + (size_t)node * NIN;
        float acc = b[c];
#pragma unroll
        for (int k = 0; k < NIN; ++k) acc = fmaf(xr[k], sW[k * H + c], acc);
        h[(size_t)node * H + c] = fmaxf(acc, 0.f);
    }
}

// ---------------- CSR build ----------------
__global__ __launch_bounds__(256) void k_hist(const int* __restrict__ dst, int* __restrict__ deg) {
    int e = blockIdx.x * 256 + threadIdx.x;
    if (e < NE) atomicAdd(&deg[dst[e]], 1);
}

// 1024 elems per block, 256 threads x 4
__global__ __launch_bounds__(256) void k_scan1(const int* __restrict__ deg, int* __restrict__ ex,
                                               int* __restrict__ totals) {
    __shared__ int s[256];
    int t = threadIdx.x, b = blockIdx.x;
    int base = b * 1024 + t * 4;
    int v0 = (base + 0 < NN) ? deg[base + 0] : 0;
    int v1 = (base + 1 < NN) ? deg[base + 1] : 0;
    int v2 = (base + 2 < NN) ? deg[base + 2] : 0;
    int v3 = (base + 3 < NN) ? deg[base + 3] : 0;
    int t0 = v0, t1 = t0 + v1, t2 = t1 + v2, tsum = t2 + v3;
    s[t] = tsum;
    __syncthreads();
#pragma unroll
    for (int d = 1; d < 256; d <<= 1) {
        int add = (t >= d) ? s[t - d] : 0;
        __syncthreads();
        s[t] += add;
        __syncthreads();
    }
    int excl = s[t] - tsum;
    ex[base + 0] = excl;
    ex[base + 1] = excl + t0;
    ex[base + 2] = excl + t1;
    ex[base + 3] = excl + t2;
    if (t == 255) totals[b] = s[t];
}

__global__ void k_scan2(const int* __restrict__ totals, int* __restrict__ boff) {
    __shared__ int s[256];
    int t = threadIdx.x;
    int v = (t < 98) ? totals[t] : 0;
    s[t] = v;
    __syncthreads();
#pragma unroll
    for (int d = 1; d < 256; d <<= 1) {
        int add = (t >= d) ? s[t - d] : 0;
        __syncthreads();
        s[t] += add;
        __syncthreads();
    }
    if (t < 98) boff[t] = s[t] - v;
}

__global__ __launch_bounds__(256) void k_scan3(const int* __restrict__ ex, const int* __restrict__ boff,
                                               int* __restrict__ rowptr, int* __restrict__ cursor) {
    int i = blockIdx.x * 256 + threadIdx.x;
    if (i < NN) {
        int r = ex[i] + boff[i >> 10];
        rowptr[i] = r;
        cursor[i] = r;
    }
    if (i == 0) rowptr[NN] = NE;
}

__global__ __launch_bounds__(256) void k_scatter(const int* __restrict__ dst, int* __restrict__ cursor,
                                                 int* __restrict__ eids) {
    int e = blockIdx.x * 256 + threadIdx.x;
    if (e < NE) {
        int p = atomicAdd(&cursor[dst[e]], 1);
        eids[p] = e;
    }
}

__global__ void k_prm_id(float* __restrict__ prm) {
    int c = threadIdx.x;  // 128
    prm[c] = 1.f;
    prm[H + c] = 0.f;
}

// ------- aggregate: agg[n] = sum_e relu( relu(sc*hsrc[src]+sh) + relu(ea@We+be) ) -------
__global__ __launch_bounds__(256) void k_agg(const int* __restrict__ rowptr, const int* __restrict__ eids,
                                             const int* __restrict__ src, const float* __restrict__ ea,
                                             const float* __restrict__ We, const float* __restrict__ be,
                                             const float* __restrict__ hsrc, const float* __restrict__ prm,
                                             float* __restrict__ agg) {
    int tid = threadIdx.x;
    int c = tid & 127, grp = tid >> 7;
    float wcol[EIN];
#pragma unroll
    for (int k = 0; k < EIN; ++k) wcol[k] = We[k * H + c];
    float bec = be[c], sc = prm[c], sh = prm[H + c];
    int nb = blockIdx.x * 8;  // 12500 blocks * 8 nodes
#pragma unroll
    for (int rep = 0; rep < 4; ++rep) {
        int n = nb + rep * 2 + grp;
        int s0 = rowptr[n], s1 = rowptr[n + 1];
        float acc = 0.f;
        for (int idx = s0; idx < s1; ++idx) {
            int eid = eids[idx];
            int sv = src[eid];
            const float4* ear = (const float4*)(ea + (size_t)eid * EIN);
            float4 e0 = ear[0], e1 = ear[1], e2 = ear[2], e3 = ear[3];
            float p = bec;
            p = fmaf(e0.x, wcol[0], p);  p = fmaf(e0.y, wcol[1], p);
            p = fmaf(e0.z, wcol[2], p);  p = fmaf(e0.w, wcol[3], p);
            p = fmaf(e1.x, wcol[4], p);  p = fmaf(e1.y, wcol[5], p);
            p = fmaf(e1.z, wcol[6], p);  p = fmaf(e1.w, wcol[7], p);
            p = fmaf(e2.x, wcol[8], p);  p = fmaf(e2.y, wcol[9], p);
            p = fmaf(e2.z, wcol[10], p); p = fmaf(e2.w, wcol[11], p);
            p = fmaf(e3.x, wcol[12], p); p = fmaf(e3.y, wcol[13], p);
            p = fmaf(e3.z, wcol[14], p); p = fmaf(e3.w, wcol[15], p);
            p = fmaxf(p, 0.f);
            float hv = hsrc[(size_t)sv * H + c];
            hv = fmaxf(fmaf(sc, hv, sh), 0.f);
            acc += fmaxf(hv + p, 0.f);
        }
        agg[(size_t)n * H + c] = acc;
    }
}

// ---- MLP per 32-node tile, register-blocked; z2 written in-place into agg ----
__global__ __launch_bounds__(256) void k_mlp(const float* __restrict__ hsrc,
                                             const float* __restrict__ prm,
                                             float* __restrict__ agg,  // in: agg, out: z2
                                             const float* __restrict__ w1,
                                             const float* __restrict__ b1,
                                             const float* __restrict__ w2,
                                             const float* __restrict__ b2,
                                             float* __restrict__ stats) {
    __shared__ float sz[32 * H];   // 16 KB  [node][128]
    __shared__ float st[32 * H2];  // 32 KB  [node][256]
    __shared__ float ls[2 * H];    // 1 KB
    int tid = threadIdx.x;
    int base = blockIdx.x * 32;  // 3125 * 32 == 100000
    ls[tid < 256 ? tid : 0] = 0.f;

    // phase 1: z = relu(sc*h+sh) + agg -> LDS (vectorized)
    float4* sz4 = (float4*)sz;
    const float4* X4 = (const float4*)hsrc;
    const float4* A4 = (const float4*)agg;
#pragma unroll
    for (int it = 0; it < 4; ++it) {
        int chunk = tid + it * 256;           // 0..1023
        int n = chunk >> 5;                   // local node
        int c4 = (chunk & 31);                // float4 index within row
        const float4 sc4 = *(const float4*)&prm[c4 * 4];
        const float4 sh4 = *(const float4*)&prm[H + c4 * 4];
        size_t gi = (size_t)(base + n) * 32 + c4;
        float4 hv = X4[gi], av = A4[gi];
        float4 z;
        z.x = fmaxf(fmaf(sc4.x, hv.x, sh4.x), 0.f) + av.x;
        z.y = fmaxf(fmaf(sc4.y, hv.y, sh4.y), 0.f) + av.y;
        z.z = fmaxf(fmaf(sc4.z, hv.z, sh4.z), 0.f) + av.z;
        z.w = fmaxf(fmaf(sc4.w, hv.w, sh4.w), 0.f) + av.w;
        sz4[chunk] = z;
    }
    __syncthreads();

    // phase 2: t = relu(z @ w1 + b1). thread: cols c64*4..+3, nodes ng*8..+7
    {
        int c64 = tid & 63, ng = tid >> 6;
        const float4* W14 = (const float4*)w1;  // [128][64] of float4
        float4 acc[8];
        float4 b1v = *(const float4*)&b1[c64 * 4];
#pragma unroll
        for (int n = 0; n < 8; ++n) acc[n] = b1v;
        for (int k0 = 0; k0 < H; k0 += 4) {
            float4 wv0 = W14[(k0 + 0) * 64 + c64];
            float4 wv1 = W14[(k0 + 1) * 64 + c64];
            float4 wv2 = W14[(k0 + 2) * 64 + c64];
            float4 wv3 = W14[(k0 + 3) * 64 + c64];
#pragma unroll
            for (int n = 0; n < 8; ++n) {
                float4 zv = sz4[(ng * 8 + n) * 32 + (k0 >> 2)];
                acc[n].x = fmaf(zv.x, wv0.x, acc[n].x); acc[n].y = fmaf(zv.x, wv0.y, acc[n].y);
                acc[n].z = fmaf(zv.x, wv0.z, acc[n].z); acc[n].w = fmaf(zv.x, wv0.w, acc[n].w);
                acc[n].x = fmaf(zv.y, wv1.x, acc[n].x); acc[n].y = fmaf(zv.y, wv1.y, acc[n].y);
                acc[n].z = fmaf(zv.y, wv1.z, acc[n].z); acc[n].w = fmaf(zv.y, wv1.w, acc[n].w);
                acc[n].x = fmaf(zv.z, wv2.x, acc[n].x); acc[n].y = fmaf(zv.z, wv2.y, acc[n].y);
                acc[n].z = fmaf(zv.z, wv2.z, acc[n].z); acc[n].w = fmaf(zv.z, wv2.w, acc[n].w);
                acc[n].x = fmaf(zv.w, wv3.x, acc[n].x); acc[n].y = fmaf(zv.w, wv3.y, acc[n].y);
                acc[n].z = fmaf(zv.w, wv3.z, acc[n].z); acc[n].w = fmaf(zv.w, wv3.w, acc[n].w);
            }
        }
        float4* st4 = (float4*)st;
#pragma unroll
        for (int n = 0; n < 8; ++n) {
            float4 r;
            r.x = fmaxf(acc[n].x, 0.f); r.y = fmaxf(acc[n].y, 0.f);
            r.z = fmaxf(acc[n].z, 0.f); r.w = fmaxf(acc[n].w, 0.f);
            st4[(ng * 8 + n) * 64 + c64] = r;
        }
    }
    __syncthreads();

    // phase 3: z2 = t @ w2 + b2. thread: cols c32*4..+3, nodes ng8*4..+3
    {
        int c32 = tid & 31, ng = tid >> 5;
        const float4* W24 = (const float4*)w2;  // [256][32] of float4
        const float4* st4 = (const float4*)st;
        float4 acc2[4];
        float4 b2v = *(const float4*)&b2[c32 * 4];
#pragma unroll
        for (int n = 0; n < 4; ++n) acc2[n] = b2v;
        for (int j0 = 0; j0 < H2; j0 += 4) {
            float4 wv0 = W24[(j0 + 0) * 32 + c32];
            float4 wv1 = W24[(j0 + 1) * 32 + c32];
            float4 wv2 = W24[(j0 + 2) * 32 + c32];
            float4 wv3 = W24[(j0 + 3) * 32 + c32];
#pragma unroll
            for (int n = 0; n < 4; ++n) {
                float4 tv = st4[(ng * 4 + n) * 64 + (j0 >> 2)];
                acc2[n].x = fmaf(tv.x, wv0.x, acc2[n].x); acc2[n].y = fmaf(tv.x, wv0.y, acc2[n].y);
                acc2[n].z = fmaf(tv.x, wv0.z, acc2[n].z); acc2[n].w = fmaf(tv.x, wv0.w, acc2[n].w);
                acc2[n].x = fmaf(tv.y, wv1.x, acc2[n].x); acc2[n].y = fmaf(tv.y, wv1.y, acc2[n].y);
                acc2[n].z = fmaf(tv.y, wv1.z, acc2[n].z); acc2[n].w = fmaf(tv.y, wv1.w, acc2[n].w);
                acc2[n].x = fmaf(tv.z, wv2.x, acc2[n].x); acc2[n].y = fmaf(tv.z, wv2.y, acc2[n].y);
                acc2[n].z = fmaf(tv.z, wv2.z, acc2[n].z); acc2[n].w = fmaf(tv.z, wv2.w, acc2[n].w);
                acc2[n].x = fmaf(tv.w, wv3.x, acc2[n].x); acc2[n].y = fmaf(tv.w, wv3.y, acc2[n].y);
                acc2[n].z = fmaf(tv.w, wv3.z, acc2[n].z); acc2[n].w = fmaf(tv.w, wv3.w, acc2[n].w);
            }
        }
        float4* O4 = (float4*)agg;
        float4 sv = {0, 0, 0, 0}, qv = {0, 0, 0, 0};
#pragma unroll
        for (int n = 0; n < 4; ++n) {
            O4[(size_t)(base + ng * 4 + n) * 32 + c32] = acc2[n];
            sv.x += acc2[n].x; sv.y += acc2[n].y; sv.z += acc2[n].z; sv.w += acc2[n].w;
            qv.x += acc2[n].x * acc2[n].x; qv.y += acc2[n].y * acc2[n].y;
            qv.z += acc2[n].z * acc2[n].z; qv.w += acc2[n].w * acc2[n].w;
        }
        int cb = c32 * 4;
        atomicAdd(&ls[cb + 0], sv.x); atomicAdd(&ls[cb + 1], sv.y);
        atomicAdd(&ls[cb + 2], sv.z); atomicAdd(&ls[cb + 3], sv.w);
        atomicAdd(&ls[H + cb + 0], qv.x); atomicAdd(&ls[H + cb + 1], qv.y);
        atomicAdd(&ls[H + cb + 2], qv.z); atomicAdd(&ls[H + cb + 3], qv.w);
    }
    __syncthreads();
    if (tid < 256) atomicAdd(&stats[tid], ls[tid]);
}

// ---------------- BN finalize into prm slot ----------------
__global__ void k_bn_fin(const float* __restrict__ stats, const float* __restrict__ gamma,
                         const float* __restrict__ beta, float* __restrict__ prm) {
    int c = threadIdx.x;  // 128
    float mean = stats[c] * (1.f / NN);
    float var = stats[H + c] * (1.f / NN) - mean * mean;
    float sc = gamma[c] * rsqrtf(var + 1e-5f);
    prm[c] = sc;
    prm[H + c] = beta[c] - mean * sc;
}

// ---------------- pool: out-sum of relu(sc*z2+sh), batch sorted -> run-flush ----------------
__global__ __launch_bounds__(256) void k_pool(const float* __restrict__ z2, const float* __restrict__ prm,
                                              const int* __restrict__ batch, float* __restrict__ sums,
                                              float* __restrict__ cntf) {
    int tid = threadIdx.x;
    int c = tid & 127, half = tid >> 7;
    float sc = prm[c], sh = prm[H + c];
    int n0 = blockIdx.x * 64 + half * 32;
    float acc = 0.f;
    int curg = -1, runlen = 0;
    for (int i = 0; i < 32; ++i) {
        int n = n0 + i;
        if (n >= NN) break;
        int g = batch[n];
        float v = fmaxf(fmaf(sc, z2[(size_t)n * H + c], sh), 0.f);
        if (g != curg) {
            if (curg >= 0) {
                atomicAdd(&sums[(size_t)curg * H + c], acc);
                if (c == 0) atomicAdd(&cntf[curg], (float)runlen);
            }
            curg = g; acc = v; runlen = 1;
        } else {
            acc += v; runlen++;
        }
    }
    if (curg >= 0) {
        atomicAdd(&sums[(size_t)curg * H + c], acc);
        if (c == 0) atomicAdd(&cntf[curg], (float)runlen);
    }
}

__global__ void k_pool_fin(const float* __restrict__ sums, const float* __restrict__ cntf,
                           float* __restrict__ out) {
    int i = blockIdx.x * blockDim.x + threadIdx.x;  // 65536 = NG*H
    if (i < NG * H) {
        int g = i >> 7;
        out[i] = sums[i] / fmaxf(cntf[g], 1.f);
    }
}

extern "C" void kernel_launch(void* const* d_in, const int* in_sizes, int n_in,
                              void* d_out, int out_size, void* d_ws, size_t ws_size,
                              hipStream_t stream) {
    const float* x      = (const float*)d_in[0];
    const int*   ei     = (const int*)d_in[1];
    const float* ea     = (const float*)d_in[2];
    const int*   batch  = (const int*)d_in[3];
    const float* node_w = (const float*)d_in[4];
    const float* node_b = (const float*)d_in[5];
    const float* edge_w = (const float*)d_in[6];
    const float* edge_b = (const float*)d_in[7];
    const float* w1     = (const float*)d_in[8];
    const float* b1     = (const float*)d_in[9];
    const float* w2     = (const float*)d_in[10];
    const float* b2     = (const float*)d_in[11];
    const float* gamma  = (const float*)d_in[12];
    const float* beta   = (const float*)d_in[13];
    float* out = (float*)d_out;

    char* ws = (char*)d_ws;
    const size_t SZ_H = (size_t)NN * H * 4;  // 51,200,000 B (16B aligned)
    float* X     = (float*)(ws);
    float* Y     = (float*)(ws + SZ_H);
    char*  tail  = ws + 2 * SZ_H;
    float* stats = (float*)(tail);                  // 256 f
    float* prm   = (float*)(tail + 1024);           // 5*256 f
    float* pool  = (float*)(tail + 1024 + 8192);    // 65536 f
    float* cntf  = (float*)(tail + 1024 + 8192 + 262144);  // 512 f
    char*  itail = tail + 1024 + 8192 + 262144 + 2048;
    int* deg    = (int*)(itail);                    // 100352
    int* ex     = deg + 100352;
    int* totals = ex + 100352;                      // 128
    int* boff   = totals + 128;                     // 128
    int* rowptr = boff + 128;                       // 100352 (incl. NN slot)
    int* cursor = rowptr + 100352;
    int* eids   = cursor + 100352;                  // 640000

    const int* srcp = ei;
    const int* dstp = ei + NE;

    // CSR build (once; reused across layers)
    hipMemsetAsync(deg, 0, 100352 * sizeof(int), stream);
    k_hist<<<2500, 256, 0, stream>>>(dstp, deg);
    k_scan1<<<98, 256, 0, stream>>>(deg, ex, totals);
    k_scan2<<<1, 256, 0, stream>>>(totals, boff);
    k_scan3<<<392, 256, 0, stream>>>(ex, boff, rowptr, cursor);
    k_scatter<<<2500, 256, 0, stream>>>(dstp, cursor, eids);

    k_prm_id<<<1, 128, 0, stream>>>(prm);
    k_node_proj<<<2048, 256, 0, stream>>>(x, node_w, node_b, X);

    float* hs = X;
    float* ag = Y;
    for (int l = 0; l < NL; ++l) {
        hipMemsetAsync(stats, 0, 256 * sizeof(float), stream);
        k_agg<<<12500, 256, 0, stream>>>(rowptr, eids, srcp, ea, edge_w, edge_b,
                                         hs, prm + l * 256, ag);
        k_mlp<<<3125, 256, 0, stream>>>(hs, prm + l * 256, ag,
                                        w1 + (size_t)l * H * H2, b1 + (size_t)l * H2,
                                        w2 + (size_t)l * H2 * H, b2 + (size_t)l * H, stats);
        k_bn_fin<<<1, 128, 0, stream>>>(stats, gamma + (size_t)l * H, beta + (size_t)l * H,
                                        prm + (l + 1) * 256);
        float* tmp = hs; hs = ag; ag = tmp;
    }

    hipMemsetAsync(pool, 0, (NG * H + NG) * sizeof(float), stream);
    k_pool<<<1563, 256, 0, stream>>>(hs, prm + NL * 256, batch, pool, cntf);
    k_pool_fin<<<256, 256, 0, stream>>>(pool, cntf, out);
}